// Round 1
// baseline (567.276 us; speedup 1.0000x reference)
//
#include <hip/hip_runtime.h>
#include <math.h>

// Problem constants (match reference)
#define BB 16384
#define DD 128
#define LL 20

// One wave (64 threads) per block, one row of xw per thread.
// W's 20 gathered rows (10 KB) staged in LDS; reads are wave-uniform -> broadcast.
__global__ __launch_bounds__(64) void hs_kernel(
    const float* __restrict__ xw,      // (B, D)
    const float* __restrict__ W,       // (N, D)
    const float* __restrict__ h_code,  // (L,)
    const int*   __restrict__ h_path,  // (L,)
    float* __restrict__ out)           // (B, 1)
{
    __shared__ float4 Ws[LL * (DD / 4)];   // 20 rows x 32 float4 = 10 KB
    __shared__ float  codes[LL];

    const int tid = threadIdx.x;

    // Stage gathered W rows into LDS (64 threads x 10 iters = 640 float4)
    for (int i = tid; i < LL * (DD / 4); i += 64) {
        const int l = i >> 5;          // row within path
        const int c = i & 31;          // float4 chunk within row
        const long long row = (long long)h_path[l];
        Ws[i] = ((const float4*)W)[row * (DD / 4) + c];
    }
    if (tid < LL) codes[tid] = h_code[tid];
    __syncthreads();

    const int b = blockIdx.x * 64 + tid;
    const float4* x4 = (const float4*)(xw + (size_t)b * DD);

    float z[LL];
#pragma unroll
    for (int l = 0; l < LL; ++l) z[l] = 0.0f;

    // D loop in float4 chunks; inner l loop fully unrolled (20 indep FMA chains)
#pragma unroll 4
    for (int c = 0; c < DD / 4; ++c) {
        const float4 x = x4[c];
#pragma unroll
        for (int l = 0; l < LL; ++l) {
            const float4 w = Ws[l * (DD / 4) + c];
            z[l] += x.x * w.x + x.y * w.y + x.z * w.z + x.w * w.w;
        }
    }

    // p_l = code*log_sigmoid(z) + (1-code)*log_sigmoid(-z)
    //     = -softplus(-z) - (1-code)*z          (exact identity)
    // softplus(t) = max(t,0) + log1p(exp(-|t|)) (stable)
    float s = 0.0f;
#pragma unroll
    for (int l = 0; l < LL; ++l) {
        const float zl = z[l];
        const float t  = -zl;
        const float sp = fmaxf(t, 0.0f) + log1pf(expf(-fabsf(t)));
        s -= sp + (1.0f - codes[l]) * zl;
    }
    out[b] = s;
}

extern "C" void kernel_launch(void* const* d_in, const int* in_sizes, int n_in,
                              void* d_out, int out_size, void* d_ws, size_t ws_size,
                              hipStream_t stream) {
    const float* xw     = (const float*)d_in[0];
    const float* W      = (const float*)d_in[1];
    const float* h_code = (const float*)d_in[2];
    const int*   h_path = (const int*)d_in[3];
    float* out = (float*)d_out;

    hs_kernel<<<BB / 64, 64, 0, stream>>>(xw, W, h_code, h_path, out);
}

// Round 2
// 553.384 us; speedup vs baseline: 1.0251x; 1.0251x over previous
//
#include <hip/hip_runtime.h>
#include <math.h>

// Problem constants (match reference)
#define BB 16384
#define DD 128
#define LL 20
#define ROWS_PER_BLOCK 64
#define THREADS 256          // 4 threads per row -> 4 waves/CU (vs 1 in v1)

// Grid = 256 blocks (1 per CU). Each block stages the 20 gathered W rows
// (10 KB) in LDS, then 4 threads cooperate per xw row: thread p handles
// float4 chunks c = p + 4j (j=0..7), so lanes 4r..4r+3 read 64 contiguous
// bytes of row r (coalesced), and LDS reads are 16-lane broadcasts.
__global__ __launch_bounds__(THREADS) void hs_kernel(
    const float* __restrict__ xw,      // (B, D)
    const float* __restrict__ W,       // (N, D)
    const float* __restrict__ h_code,  // (L,)
    const int*   __restrict__ h_path,  // (L,)
    float* __restrict__ out)           // (B, 1)
{
    __shared__ float4 Ws[LL * (DD / 4)];   // 20 rows x 32 float4 = 10 KB
    __shared__ float  codes[LL];

    const int tid = threadIdx.x;

    // Stage gathered W rows into LDS
    for (int i = tid; i < LL * (DD / 4); i += THREADS) {
        const int l = i >> 5;          // path index
        const int c = i & 31;          // float4 chunk within row
        Ws[i] = ((const float4*)W)[(long long)h_path[l] * (DD / 4) + c];
    }
    if (tid < LL) codes[tid] = h_code[tid];
    __syncthreads();

    const int p   = tid & 3;                       // which quarter of D
    const int r   = tid >> 2;                      // row within block
    const int row = blockIdx.x * ROWS_PER_BLOCK + r;
    const float4* x4 = (const float4*)xw + (size_t)row * (DD / 4);

    float z[LL];
#pragma unroll
    for (int l = 0; l < LL; ++l) z[l] = 0.0f;

#pragma unroll
    for (int j = 0; j < 8; ++j) {
        const int c = p + 4 * j;
        const float4 x = x4[c];
#pragma unroll
        for (int l = 0; l < LL; ++l) {
            const float4 w = Ws[l * (DD / 4) + c];
            z[l] += x.x * w.x + x.y * w.y + x.z * w.z + x.w * w.w;
        }
    }

    // Combine the 4 partial dots per row (lanes 4r..4r+3 are in one wave)
#pragma unroll
    for (int l = 0; l < LL; ++l) {
        z[l] += __shfl_xor(z[l], 1);
        z[l] += __shfl_xor(z[l], 2);
    }

    if (p == 0) {
        // p_l = code*log_sigmoid(z) + (1-code)*log_sigmoid(-z)
        //     = -softplus(-z) - (1-code)*z       (exact identity)
        float s = 0.0f;
#pragma unroll
        for (int l = 0; l < LL; ++l) {
            const float zl = z[l];
            const float t  = -zl;
            const float sp = fmaxf(t, 0.0f) + log1pf(expf(-fabsf(t)));
            s -= sp + (1.0f - codes[l]) * zl;
        }
        out[row] = s;
    }
}

extern "C" void kernel_launch(void* const* d_in, const int* in_sizes, int n_in,
                              void* d_out, int out_size, void* d_ws, size_t ws_size,
                              hipStream_t stream) {
    const float* xw     = (const float*)d_in[0];
    const float* W      = (const float*)d_in[1];
    const float* h_code = (const float*)d_in[2];
    const int*   h_path = (const int*)d_in[3];
    float* out = (float*)d_out;

    hs_kernel<<<BB / ROWS_PER_BLOCK, THREADS, 0, stream>>>(xw, W, h_code, h_path, out);
}